// Round 9
// baseline (605.109 us; speedup 1.0000x reference)
//
#include <hip/hip_runtime.h>
#include <stdint.h>

typedef _Float16 f16;
typedef _Float16 f16x8 __attribute__((ext_vector_type(8)));
typedef float f32x4 __attribute__((ext_vector_type(4)));

union U4 { uint4 u; f16 h[8]; };
union U2 { uint2 u; f16 h[4]; };

// async global->LDS, 16B per lane; LDS dest = wave-uniform base + lane*16
#define GLOAD16(g, l)                                                         \
  __builtin_amdgcn_global_load_lds(                                           \
      (const __attribute__((address_space(1))) void*)(g),                     \
      (__attribute__((address_space(3))) void*)(l), 16, 0, 0)

// ---------------- weight transpose + cvt: Wt[n][k] = (f16)W[k][n], all four at once ----
__global__ __launch_bounds__(256) void k_wt(const float* __restrict__ W0,
                                            const float* __restrict__ W1,
                                            const float* __restrict__ W2,
                                            const float* __restrict__ W3,
                                            f16* __restrict__ T0, f16* __restrict__ T1,
                                            f16* __restrict__ T2, f16* __restrict__ T3) {
    __shared__ f16 tile[64 * 65];
    int z = blockIdx.z;
    const float* W = z == 0 ? W0 : z == 1 ? W1 : z == 2 ? W2 : W3;
    f16* Wt = z == 0 ? T0 : z == 1 ? T1 : z == 2 ? T2 : T3;
    int t = threadIdx.x;
    int k0 = blockIdx.x * 64, n0 = blockIdx.y * 64;
    #pragma unroll
    for (int i = 0; i < 4; i++) {
        int cid = t + i * 256;           // 1024 chunks of 4 floats
        int row = cid >> 4, c4 = cid & 15;
        float4 v = *(const float4*)(W + (size_t)(k0 + row) * 1024 + n0 + c4 * 4);
        tile[(c4 * 4 + 0) * 65 + row] = (f16)v.x;
        tile[(c4 * 4 + 1) * 65 + row] = (f16)v.y;
        tile[(c4 * 4 + 2) * 65 + row] = (f16)v.z;
        tile[(c4 * 4 + 3) * 65 + row] = (f16)v.w;
    }
    __syncthreads();
    #pragma unroll
    for (int i = 0; i < 2; i++) {
        int cid = t + i * 256;
        int nr = cid >> 3, kc = cid & 7;
        U4 u;
        #pragma unroll
        for (int j = 0; j < 8; j++) u.h[j] = tile[nr * 65 + kc * 8 + j];
        *(uint4*)(Wt + (size_t)(n0 + nr) * 1024 + k0 + kc * 8) = u.u;
    }
}

// ---------------- Gram matrices: TRANS=0: C = pc^T@pc (512x512, K=256)
//                                 TRANS=1: C = pc@pc^T (256x256, K=512) -----------------
template <int TRANS>
__global__ __launch_bounds__(256) void k_gram(const float* __restrict__ pc,
                                              float* __restrict__ out) {
    constexpr int N = TRANS ? 256 : 512;
    constexpr int K = TRANS ? 512 : 256;
    __shared__ float As[16][68];
    __shared__ float Bs[16][68];
    int t = threadIdx.x;
    int i0 = blockIdx.x * 64, j0 = blockIdx.y * 64;
    int ty = t >> 4, tx = t & 15;
    float acc[4][4];
    #pragma unroll
    for (int r = 0; r < 4; r++)
        #pragma unroll
        for (int c = 0; c < 4; c++) acc[r][c] = 0.f;

    for (int kt = 0; kt < K; kt += 16) {
        if (TRANS == 0) {
            int k = t >> 4, c4 = t & 15;
            float4 va = *(const float4*)(pc + (size_t)(kt + k) * 512 + i0 + c4 * 4);
            float4 vb = *(const float4*)(pc + (size_t)(kt + k) * 512 + j0 + c4 * 4);
            *(float4*)&As[k][c4 * 4] = va;
            *(float4*)&Bs[k][c4 * 4] = vb;
        } else {
            int r = t >> 2, kc = t & 3;
            float4 va = *(const float4*)(pc + (size_t)(i0 + r) * 512 + kt + kc * 4);
            As[kc * 4 + 0][r] = va.x; As[kc * 4 + 1][r] = va.y;
            As[kc * 4 + 2][r] = va.z; As[kc * 4 + 3][r] = va.w;
            float4 vb = *(const float4*)(pc + (size_t)(j0 + r) * 512 + kt + kc * 4);
            Bs[kc * 4 + 0][r] = vb.x; Bs[kc * 4 + 1][r] = vb.y;
            Bs[kc * 4 + 2][r] = vb.z; Bs[kc * 4 + 3][r] = vb.w;
        }
        __syncthreads();
        #pragma unroll
        for (int u = 0; u < 16; u++) {
            float4 av = *(const float4*)&As[u][ty * 4];
            float4 bv = *(const float4*)&Bs[u][tx * 4];
            float aa[4] = {av.x, av.y, av.z, av.w};
            float bb[4] = {bv.x, bv.y, bv.z, bv.w};
            #pragma unroll
            for (int r = 0; r < 4; r++)
                #pragma unroll
                for (int c = 0; c < 4; c++) acc[r][c] += aa[r] * bb[c];
        }
        __syncthreads();
    }
    #pragma unroll
    for (int r = 0; r < 4; r++)
        #pragma unroll
        for (int c = 0; c < 4; c++)
            out[(size_t)(i0 + ty * 4 + r) * N + j0 + tx * 4 + c] = acc[r][c];
}

// ---------------- mask: M from precomputed gram blocks, then 1->50->1 MLP --------------
// Output pre-scaled by 0.125*log2(e): attn softmax runs in the exp2 domain.
__global__ __launch_bounds__(256) void k_mask(const float* __restrict__ pc,
                                              const float* __restrict__ nn,
                                              const float* __restrict__ nknk,
                                              const float* __restrict__ mw1,
                                              const float* __restrict__ mb1,
                                              const float* __restrict__ mw2,
                                              const float* __restrict__ mb2,
                                              float* __restrict__ maskp) {
    __shared__ float w1[50], b1[50], w2[50];
    int t = threadIdx.x;
    if (t < 50) { w1[t] = mw1[t]; b1[t] = mb1[t]; w2[t] = mw2[t]; }
    __syncthreads();
    int id = blockIdx.x * 256 + t;
    int i = id / 768, j = id - i * 768;
    float M;
    if (i < 512) M = (j < 512) ? nn[(size_t)i * 512 + j] : pc[(size_t)(j - 512) * 512 + i];
    else         M = (j < 512) ? pc[(size_t)(i - 512) * 512 + j]
                               : nknk[(size_t)(i - 512) * 256 + (j - 512)];
    float acc = mb2[0];
    #pragma unroll 10
    for (int u = 0; u < 50; u++) acc += fmaxf(M * w1[u] + b1[u], 0.f) * w2[u];
    maskp[id] = acc * 0.18033688011112042f;   // 0.125 * log2(e)
}

// ---------------- per-head V transpose: VT[bh][d=64][s=768] ----------------------------
__global__ __launch_bounds__(256) void k_vt(const f16* __restrict__ Vh,
                                            f16* __restrict__ VT) {
    __shared__ f16 tile[64][72];
    int t = threadIdx.x;
    int s0 = blockIdx.x * 64;
    int bh = blockIdx.y, b = bh >> 4, h = bh & 15;
    #pragma unroll
    for (int p = 0; p < 2; p++) {
        int cid = t + p * 256;           // 512 uint4 chunks: 64 s x 8 dc
        int s = cid >> 3, dc = cid & 7;
        *(uint4*)&tile[s][dc * 8] =
            *(const uint4*)(Vh + ((size_t)b * 768 + s0 + s) * 1024 + h * 64 + dc * 8);
    }
    __syncthreads();
    #pragma unroll
    for (int p = 0; p < 2; p++) {
        int cid = t + p * 256;
        int d = cid >> 3, sc = cid & 7;
        U4 u;
        #pragma unroll
        for (int j = 0; j < 8; j++) u.h[j] = tile[sc * 8 + j][d];
        *(uint4*)(VT + ((size_t)bh * 64 + d) * 768 + s0 + sc * 8) = u.u;
    }
}

// ---------------- fused GEMM: C = (f16)A_f32(12288x1024) @ W(1024x1024) + bias ---------
// A read DIRECTLY as f32 (cvt fused): staged via global_load_lds into a 16KB f32 tile
// ([128][32] floats, 128B rows = 8 x 16B slots, slot swizzle p -> p^(row&7) both sides;
// 128B row stride covers all 32 banks -> swizzled reads 2-way=free). Fragments read as
// 2x f32x4, converted in-register with RTN (f16) casts == old k_cvt numerics exactly.
// Single-buffered 2-barrier loop (dbuf measured neutral r7). 1-D grid, XCD decode.
// MODE 0: f16 out. MODE 1: f16 hi/lo split.
template <int MODE>
__global__ __launch_bounds__(256) void k_gemma(const float* __restrict__ A,
                                               const f16* __restrict__ Bt,
                                               const float* __restrict__ bias,
                                               void* out0v, void* out1v) {
    __shared__ float Asf[128 * 32];      // 16KB f32 A tile
    __shared__ f16 Bs[128 * 32];         // 8KB f16 B tile
    int t = threadIdx.x;
    int w = t >> 6, lane = t & 63, l15 = lane & 15, quad = lane >> 4;
    int wm = w >> 1, wn = w & 1;
    int id = blockIdx.x;                 // 768 = 96 row-panels x 8 col-panels
    int rest = id >> 3;
    int row0 = ((id & 7) * 12 + rest % 12) * 128;
    int n0 = (rest / 12) * 128;

    // A staging: 4 rounds; round p covers rows p*32 + w*8 + (lane>>3), slot lane&7.
    // row&7 == lane>>3, so the swizzled source slot is round-invariant.
    int ar = lane >> 3;
    int ss_a = (lane & 7) ^ ar;
    const float* gA = A + (size_t)(row0 + w * 8 + ar) * 1024 + ss_a * 4;
    // B staging: 2 rounds (as before), slot swizzle (m>>1)&3
    int m0 = w * 16 + (lane >> 2);
    int m1 = m0 + 64;
    int ks0 = (lane & 3) ^ ((m0 >> 1) & 3);
    int ks1 = (lane & 3) ^ ((m1 >> 1) & 3);
    const f16* gB0 = Bt + (size_t)(n0 + m0) * 1024 + ks0 * 8;
    const f16* gB1 = Bt + (size_t)(n0 + m1) * 1024 + ks1 * 8;
    int sw = (l15 >> 1) & 3;             // B read-side XOR
    int rx = l15 & 7;                    // A read-side XOR (row&7 == l15&7)

    f32x4 acc[4][4];
    #pragma unroll
    for (int mi = 0; mi < 4; mi++)
        #pragma unroll
        for (int ni = 0; ni < 4; ni++) acc[mi][ni] = (f32x4){0.f, 0.f, 0.f, 0.f};

    for (int kt = 0; kt < 32; kt++) {
        int k0 = kt * 32;
        #pragma unroll
        for (int p = 0; p < 4; p++)
            GLOAD16(gA + (size_t)p * 32 * 1024 + k0, &Asf[(p * 32 + w * 8) * 32]);
        GLOAD16(gB0 + k0, &Bs[w * 512]);
        GLOAD16(gB1 + k0, &Bs[w * 512 + 2048]);
        __syncthreads();                 // drains vmcnt -> tiles ready
        f16x8 af[4], bf_[4];
        #pragma unroll
        for (int mi = 0; mi < 4; mi++) {
            int arow = wm * 64 + mi * 16 + l15;
            const char* ab = (const char*)Asf + (size_t)arow * 128;
            f32x4 a0 = *(const f32x4*)(ab + ((((quad << 1) | 0) ^ rx) << 4));
            f32x4 a1 = *(const f32x4*)(ab + ((((quad << 1) | 1) ^ rx) << 4));
            U4 u;
            u.h[0] = (f16)a0[0]; u.h[1] = (f16)a0[1];
            u.h[2] = (f16)a0[2]; u.h[3] = (f16)a0[3];
            u.h[4] = (f16)a1[0]; u.h[5] = (f16)a1[1];
            u.h[6] = (f16)a1[2]; u.h[7] = (f16)a1[3];
            af[mi] = *(const f16x8*)u.h;
        }
        #pragma unroll
        for (int ni = 0; ni < 4; ni++)
            bf_[ni] = *(const f16x8*)((const char*)Bs +
                      (size_t)(wn * 64 + ni * 16 + l15) * 64 + ((quad ^ sw) << 4));
        #pragma unroll
        for (int mi = 0; mi < 4; mi++)
            #pragma unroll
            for (int ni = 0; ni < 4; ni++)
                acc[mi][ni] = __builtin_amdgcn_mfma_f32_16x16x32_f16(af[mi], bf_[ni],
                                                                     acc[mi][ni], 0, 0, 0);
        __syncthreads();                 // protect LDS reuse next iter
    }
    #pragma unroll
    for (int mi = 0; mi < 4; mi++) {
        #pragma unroll
        for (int ni = 0; ni < 4; ni++) {
            int col = n0 + wn * 64 + ni * 16 + l15;
            float bv = bias[col];
            #pragma unroll
            for (int r = 0; r < 4; r++) {
                int row = row0 + wm * 64 + mi * 16 + quad * 4 + r;
                float v = acc[mi][ni][r] + bv;
                size_t idx = (size_t)row * 1024 + col;
                if (MODE == 0) {
                    ((f16*)out0v)[idx] = (f16)v;
                } else {
                    f16 hi = (f16)v;
                    ((f16*)out0v)[idx] = hi;
                    ((f16*)out1v)[idx] = (f16)(v - (float)hi);
                }
            }
        }
    }
}

// ---------------- GEMM (f16 A): C = A(12288x1024) @ W(1024x1024) + bias, fp32 out ------
// Used for the Wo projection (A = attn output, already f16). Double-buffered (neutral
// but harmless). 1-D grid, XCD decode. XOR-swizzled staging as before.
__global__ __launch_bounds__(256) void k_gemm2(const f16* __restrict__ A,
                                               const f16* __restrict__ Bt,
                                               const float* __restrict__ bias,
                                               float* __restrict__ out0) {
    __shared__ f16 As[2][128 * 32];
    __shared__ f16 Bs[2][128 * 32];
    int t = threadIdx.x;
    int w = t >> 6, lane = t & 63, l15 = lane & 15, quad = lane >> 4;
    int wm = w >> 1, wn = w & 1;
    int id = blockIdx.x;
    int rest = id >> 3;
    int row0 = ((id & 7) * 12 + rest % 12) * 128;
    int n0 = (rest / 12) * 128;

    int m0 = w * 16 + (lane >> 2);
    int m1 = m0 + 64;
    int ks0 = (lane & 3) ^ ((m0 >> 1) & 3);
    int ks1 = (lane & 3) ^ ((m1 >> 1) & 3);
    const f16* gA0 = A + (size_t)(row0 + m0) * 1024 + ks0 * 8;
    const f16* gA1 = A + (size_t)(row0 + m1) * 1024 + ks1 * 8;
    const f16* gB0 = Bt + (size_t)(n0 + m0) * 1024 + ks0 * 8;
    const f16* gB1 = Bt + (size_t)(n0 + m1) * 1024 + ks1 * 8;
    int sw = (l15 >> 1) & 3;

    auto STAGE = [&](int bsel, int k0) {
        GLOAD16(gA0 + k0, &As[bsel][w * 512]);
        GLOAD16(gA1 + k0, &As[bsel][w * 512 + 2048]);
        GLOAD16(gB0 + k0, &Bs[bsel][w * 512]);
        GLOAD16(gB1 + k0, &Bs[bsel][w * 512 + 2048]);
    };

    f32x4 acc[4][4];
    #pragma unroll
    for (int mi = 0; mi < 4; mi++)
        #pragma unroll
        for (int ni = 0; ni < 4; ni++) acc[mi][ni] = (f32x4){0.f, 0.f, 0.f, 0.f};

    STAGE(0, 0);
    __syncthreads();
    int buf = 0;
    for (int kt = 0; kt < 32; kt++) {
        if (kt < 31) STAGE(buf ^ 1, (kt + 1) * 32);
        f16x8 af[4], bf_[4];
        #pragma unroll
        for (int mi = 0; mi < 4; mi++)
            af[mi] = *(const f16x8*)((const char*)&As[buf][0] +
                     (size_t)(wm * 64 + mi * 16 + l15) * 64 + ((quad ^ sw) << 4));
        #pragma unroll
        for (int ni = 0; ni < 4; ni++)
            bf_[ni] = *(const f16x8*)((const char*)&Bs[buf][0] +
                      (size_t)(wn * 64 + ni * 16 + l15) * 64 + ((quad ^ sw) << 4));
        #pragma unroll
        for (int mi = 0; mi < 4; mi++)
            #pragma unroll
            for (int ni = 0; ni < 4; ni++)
                acc[mi][ni] = __builtin_amdgcn_mfma_f32_16x16x32_f16(af[mi], bf_[ni],
                                                                     acc[mi][ni], 0, 0, 0);
        __syncthreads();
        buf ^= 1;
    }
    #pragma unroll
    for (int mi = 0; mi < 4; mi++) {
        #pragma unroll
        for (int ni = 0; ni < 4; ni++) {
            int col = n0 + wn * 64 + ni * 16 + l15;
            float bv = bias[col];
            #pragma unroll
            for (int r = 0; r < 4; r++) {
                int row = row0 + wm * 64 + mi * 16 + quad * 4 + r;
                out0[(size_t)row * 1024 + col] = acc[mi][ni][r] + bv;
            }
        }
    }
}

// ---------------- flash attention, swapped QK^T (S^T fragments), split-f16 QK ----------
// mfma(K,Q) -> S^T: col=l15=q, row=quad*4+r=key. Per-lane q-state; exp2-domain softmax.
// LDS 48KB (3 blocks/CU): K hi/lo double-buffered, V SINGLE-buffered for the CURRENT
// tile with counted-vmcnt sync: V loads issued BEFORE the 4 K-prefetch loads, so
// mid-tile s_waitcnt vmcnt(4) (vmcnt is FIFO) guarantees V landed without draining the
// K prefetch. Raw s_barriers (no compiler auto-drain). End-of-tile vmcnt(0) covers the
// K prefetch (had the whole compute phase to land) + Vs WAR protection.
__global__ __launch_bounds__(256) void k_attn(const f16* __restrict__ Qhi,
                                              const f16* __restrict__ Qlo,
                                              const f16* __restrict__ Khi,
                                              const f16* __restrict__ Klo,
                                              const f16* __restrict__ VT,
                                              const float* __restrict__ maskp,
                                              f16* __restrict__ Xout) {
    __shared__ f16 Ksh[2][64 * 64];
    __shared__ f16 Ksl[2][64 * 64];
    __shared__ f16 Vs[64 * 64];      // Vs[d][s], single-buffered (current tile)
    __shared__ f16 Ps[4][16 * 64];   // per-wave P [q][key], swizzled 16B slots
    int t = threadIdx.x;
    int w = t >> 6, lane = t & 63, l15 = lane & 15, quad = lane >> 4;
    int id = blockIdx.x;             // 3072 = 256 bh x 12 q-tiles
    int bh = (id & 7) + ((id >> 3) / 12) * 8;
    int q0 = ((id >> 3) % 12) * 64;
    int b = bh >> 4, h = bh & 15;
    const size_t base = ((size_t)b * 768) * 1024 + h * 64;

    // staging geometry: wave w covers rows w*16 .. w*16+15, 2 rounds of 8 rows
    int srow = lane >> 3;            // 0..7 within round
    int sslot = lane & 7;

    f16x8 qh[2], ql[2];
    int qrow = q0 + w * 16 + l15;
    #pragma unroll
    for (int c = 0; c < 2; c++) {
        qh[c] = *(const f16x8*)(Qhi + base + (size_t)qrow * 1024 + c * 32 + quad * 8);
        ql[c] = *(const f16x8*)(Qlo + base + (size_t)qrow * 1024 + c * 32 + quad * 8);
    }
    // per-lane online-softmax state for q = q0 + w*16 + l15 (replicated across quads)
    float mrow = -1e30f, lrow = 0.f;
    f32x4 o[4];                      // O^T: d = ni*16 + quad*4 + r, q = l15
    #pragma unroll
    for (int ni = 0; ni < 4; ni++) o[ni] = (f32x4){0.f, 0.f, 0.f, 0.f};

    auto STAGE_K = [&](int bsel, int k0) {
        #pragma unroll
        for (int p = 0; p < 2; p++) {
            int row = w * 16 + p * 8 + srow;
            int ss = sslot ^ (row & 7);
            GLOAD16(Khi + base + (size_t)(k0 + row) * 1024 + ss * 8,
                    &Ksh[bsel][w * 1024 + p * 512]);
            GLOAD16(Klo + base + (size_t)(k0 + row) * 1024 + ss * 8,
                    &Ksl[bsel][w * 1024 + p * 512]);
        }
    };
    auto STAGE_V = [&](int k0) {
        #pragma unroll
        for (int p = 0; p < 2; p++) {
            int row = w * 16 + p * 8 + srow;
            int ss = sslot ^ (row & 7);
            GLOAD16(VT + ((size_t)bh * 64 + row) * 768 + k0 + ss * 8,
                    &Vs[w * 1024 + p * 512]);
        }
    };

    STAGE_K(0, 0);
    asm volatile("s_waitcnt vmcnt(0)" ::: "memory");
    __builtin_amdgcn_s_barrier();
    int buf = 0;
    int kx = l15 & 7;
    const float* mbase = maskp + (size_t)quad * 4 * 768 + q0 + w * 16 + l15;

    for (int kt = 0; kt < 12; kt++) {
        int k0 = kt * 64;
        // mask loads (coalesced over l15; symmetric mask indexed [key][q])
        float mvs[4][4];
        #pragma unroll
        for (int kn = 0; kn < 4; kn++)
            #pragma unroll
            for (int r = 0; r < 4; r++)
                mvs[kn][r] = mbase[(size_t)(k0 + kn * 16 + r) * 768];
        // V for CURRENT tile first (oldest), then K prefetch for next (4 newest)
        STAGE_V(k0);
        if (kt < 11) STAGE_K(buf ^ 1, k0 + 64);

        float sv[4][4];
        #pragma unroll
        for (int kn = 0; kn < 4; kn++) {
            f32x4 s = (f32x4){0.f, 0.f, 0.f, 0.f};
            int key = kn * 16 + l15;
            #pragma unroll
            for (int c = 0; c < 2; c++) {
                int slot = ((c << 2) + quad) ^ kx;
                f16x8 kh = *(const f16x8*)((const char*)&Ksh[buf][0] +
                                           (size_t)key * 128 + (slot << 4));
                f16x8 kl = *(const f16x8*)((const char*)&Ksl[buf][0] +
                                           (size_t)key * 128 + (slot << 4));
                s = __builtin_amdgcn_mfma_f32_16x16x32_f16(kh, qh[c], s, 0, 0, 0);
                s = __builtin_amdgcn_mfma_f32_16x16x32_f16(kh, ql[c], s, 0, 0, 0);
                s = __builtin_amdgcn_mfma_f32_16x16x32_f16(kl, qh[c], s, 0, 0, 0);
            }
            #pragma unroll
            for (int r = 0; r < 4; r++) sv[kn][r] = s[r] * mvs[kn][r];
        }

        // row max: fmax triples fuse to v_max3_f32; + 2 cross-quad shuffles
        float g0 = fmaxf(fmaxf(sv[0][0], sv[0][1]), sv[0][2]);
        float g1 = fmaxf(fmaxf(sv[0][3], sv[1][0]), sv[1][1]);
        float g2 = fmaxf(fmaxf(sv[1][2], sv[1][3]), sv[2][0]);
        float g3 = fmaxf(fmaxf(sv[2][1], sv[2][2]), sv[2][3]);
        float g4 = fmaxf(fmaxf(sv[3][0], sv[3][1]), sv[3][2]);
        float tm = fmaxf(fmaxf(fmaxf(g0, g1), fmaxf(g2, g3)), fmaxf(g4, sv[3][3]));
        tm = fmaxf(tm, __shfl_xor(tm, 16));
        tm = fmaxf(tm, __shfl_xor(tm, 32));
        // defer-max (THR = 11 in exp2 domain ~ 7.6 nats)
        if (__any(tm > mrow + 11.0f)) {
            float mn = fmaxf(mrow, tm);
            float alpha = exp2f(mrow - mn);
            mrow = mn;
            lrow *= alpha;
            #pragma unroll
            for (int ni = 0; ni < 4; ni++)
                #pragma unroll
                for (int r = 0; r < 4; r++) o[ni][r] *= alpha;
        }
        // exp2, row-sum, pack P (4 consecutive keys) -> swizzled ds_write_b64
        float rs = 0.f;
        #pragma unroll
        for (int kn = 0; kn < 4; kn++) {
            U2 pk;
            #pragma unroll
            for (int r = 0; r < 4; r++) {
                float pv = exp2f(sv[kn][r] - mrow);
                rs += pv;
                pk.h[r] = (f16)pv;
            }
            int slot = (kn * 2 + (quad >> 1)) ^ kx;
            *(uint2*)((char*)&Ps[w][0] + l15 * 128 + (slot << 4) + ((quad & 1) << 3)) = pk.u;
        }
        rs += __shfl_xor(rs, 16);
        rs += __shfl_xor(rs, 32);
        lrow += rs;

        asm volatile("s_waitcnt lgkmcnt(0)" ::: "memory");  // P write -> B-frag read (same wave)
        // V(cur) ready: FIFO vmcnt, V older than the 4 K-prefetch loads
        if (kt < 11) asm volatile("s_waitcnt vmcnt(4)" ::: "memory");
        else         asm volatile("s_waitcnt vmcnt(0)" ::: "memory");
        __builtin_amdgcn_s_barrier();    // all waves' V chunks visible
        __builtin_amdgcn_sched_barrier(0);
        #pragma unroll
        for (int c = 0; c < 2; c++) {
            int pslot = ((c << 2) + quad) ^ kx;
            f16x8 pa = *(const f16x8*)((const char*)&Ps[w][0] +
                                       (size_t)l15 * 128 + (pslot << 4));
            #pragma unroll
            for (int ni = 0; ni < 4; ni++) {
                int d = ni * 16 + l15;
                f16x8 vb = *(const f16x8*)((const char*)&Vs[0] +
                                           (size_t)d * 128 + (pslot << 4));
                o[ni] = __builtin_amdgcn_mfma_f32_16x16x32_f16(vb, pa, o[ni], 0, 0, 0);
            }
        }
        // K(next) landed (whole compute phase in flight); Vs consumed by all waves
        asm volatile("s_waitcnt vmcnt(0)" ::: "memory");
        __builtin_amdgcn_s_barrier();
        buf ^= 1;
    }
    // O^T -> packed coalescing-friendly stores: 4 f16 (r) per 8B, quads form 32B runs
    float rl = 1.0f / lrow;
    int qg = q0 + w * 16 + l15;
    #pragma unroll
    for (int ni = 0; ni < 4; ni++) {
        U2 ok;
        #pragma unroll
        for (int r = 0; r < 4; r++) ok.h[r] = (f16)(o[ni][r] * rl);
        *(uint2*)(Xout + ((size_t)b * 768 + qg) * 1024 + h * 64 + ni * 16 + quad * 4) = ok.u;
    }
}

// ---------------- launch ---------------------------------------------------------------
extern "C" void kernel_launch(void* const* d_in, const int* in_sizes, int n_in,
                              void* d_out, int out_size, void* d_ws, size_t ws_size,
                              hipStream_t stream) {
    (void)in_sizes; (void)n_in; (void)out_size; (void)ws_size;
    const float* query = (const float*)d_in[0];
    const float* key   = (const float*)d_in[1];
    const float* value = (const float*)d_in[2];
    const float* pc    = (const float*)d_in[3];
    const float* Wq    = (const float*)d_in[4];
    const float* bq    = (const float*)d_in[5];
    const float* Wk    = (const float*)d_in[6];
    const float* bk    = (const float*)d_in[7];
    const float* Wv    = (const float*)d_in[8];
    const float* bv    = (const float*)d_in[9];
    const float* Wo    = (const float*)d_in[10];
    const float* bo    = (const float*)d_in[11];
    const float* mw1   = (const float*)d_in[12];
    const float* mb1   = (const float*)d_in[13];
    const float* mw2   = (const float*)d_in[14];
    const float* mb2   = (const float*)d_in[15];

    char* p = (char*)d_ws;
    auto take = [&](size_t bytes) -> char* {
        char* r = p; p += (bytes + 255) & ~(size_t)255; return r;
    };
    const size_t NTOK = 12288, DM = 1024;
    float* maskb = (float*)take(768 * 768 * 4);
    float* nnb   = (float*)take(512 * 512 * 4);
    float* nknkb = (float*)take(256 * 256 * 4);
    f16* Wqt = (f16*)take(DM * DM * 2);
    f16* Wkt = (f16*)take(DM * DM * 2);
    f16* Wvt = (f16*)take(DM * DM * 2);
    f16* Wot = (f16*)take(DM * DM * 2);
    f16* buf1 = (f16*)take(NTOK * DM * 2);
    f16* Qhi = (f16*)take(NTOK * DM * 2);
    f16* Qlo = (f16*)take(NTOK * DM * 2);
    f16* Khi = (f16*)take(NTOK * DM * 2);
    f16* Klo = (f16*)take(NTOK * DM * 2);
    f16* Vhb = (f16*)take(NTOK * DM * 2);
    f16* VTb = (f16*)take(NTOK * DM * 2);

    k_wt<<<dim3(16, 16, 4), 256, 0, stream>>>(Wq, Wk, Wv, Wo, Wqt, Wkt, Wvt, Wot);
    k_gram<0><<<dim3(8, 8), 256, 0, stream>>>(pc, nnb);
    k_gram<1><<<dim3(4, 4), 256, 0, stream>>>(pc, nknkb);
    k_mask<<<2304, 256, 0, stream>>>(pc, nnb, nknkb, mw1, mb1, mw2, mb2, maskb);

    k_gemma<1><<<768, 256, 0, stream>>>(query, Wqt, bq, Qhi, Qlo);
    k_gemma<1><<<768, 256, 0, stream>>>(key, Wkt, bk, Khi, Klo);
    k_gemma<0><<<768, 256, 0, stream>>>(value, Wvt, bv, Vhb, nullptr);

    k_vt<<<dim3(12, 256), 256, 0, stream>>>(Vhb, VTb);

    k_attn<<<3072, 256, 0, stream>>>(Qhi, Qlo, Khi, Klo, VTb, maskb, buf1);

    k_gemm2<<<768, 256, 0, stream>>>(buf1, Wot, bo, (float*)d_out);
}

// Round 10
// 557.111 us; speedup vs baseline: 1.0862x; 1.0862x over previous
//
#include <hip/hip_runtime.h>
#include <stdint.h>

typedef _Float16 f16;
typedef _Float16 f16x8 __attribute__((ext_vector_type(8)));
typedef float f32x4 __attribute__((ext_vector_type(4)));

union U4 { uint4 u; f16 h[8]; };
union U2 { uint2 u; f16 h[4]; };

// async global->LDS, 16B per lane; LDS dest = wave-uniform base + lane*16
#define GLOAD16(g, l)                                                         \
  __builtin_amdgcn_global_load_lds(                                           \
      (const __attribute__((address_space(1))) void*)(g),                     \
      (__attribute__((address_space(3))) void*)(l), 16, 0, 0)

// ---------------- weight transpose + cvt: Wt[n][k] = (f16)W[k][n], all four at once ----
__global__ __launch_bounds__(256) void k_wt(const float* __restrict__ W0,
                                            const float* __restrict__ W1,
                                            const float* __restrict__ W2,
                                            const float* __restrict__ W3,
                                            f16* __restrict__ T0, f16* __restrict__ T1,
                                            f16* __restrict__ T2, f16* __restrict__ T3) {
    __shared__ f16 tile[64 * 65];
    int z = blockIdx.z;
    const float* W = z == 0 ? W0 : z == 1 ? W1 : z == 2 ? W2 : W3;
    f16* Wt = z == 0 ? T0 : z == 1 ? T1 : z == 2 ? T2 : T3;
    int t = threadIdx.x;
    int k0 = blockIdx.x * 64, n0 = blockIdx.y * 64;
    #pragma unroll
    for (int i = 0; i < 4; i++) {
        int cid = t + i * 256;           // 1024 chunks of 4 floats
        int row = cid >> 4, c4 = cid & 15;
        float4 v = *(const float4*)(W + (size_t)(k0 + row) * 1024 + n0 + c4 * 4);
        tile[(c4 * 4 + 0) * 65 + row] = (f16)v.x;
        tile[(c4 * 4 + 1) * 65 + row] = (f16)v.y;
        tile[(c4 * 4 + 2) * 65 + row] = (f16)v.z;
        tile[(c4 * 4 + 3) * 65 + row] = (f16)v.w;
    }
    __syncthreads();
    #pragma unroll
    for (int i = 0; i < 2; i++) {
        int cid = t + i * 256;
        int nr = cid >> 3, kc = cid & 7;
        U4 u;
        #pragma unroll
        for (int j = 0; j < 8; j++) u.h[j] = tile[nr * 65 + kc * 8 + j];
        *(uint4*)(Wt + (size_t)(n0 + nr) * 1024 + k0 + kc * 8) = u.u;
    }
}

// ---------------- fp32 -> f16 elementwise ---------------------------------------------
__global__ __launch_bounds__(256) void k_cvt(const float* __restrict__ in,
                                             f16* __restrict__ out) {
    size_t id = (size_t)blockIdx.x * 256 + threadIdx.x;  // one 8-elem chunk
    float4 a = *(const float4*)(in + id * 8);
    float4 b = *(const float4*)(in + id * 8 + 4);
    U4 u;
    u.h[0] = (f16)a.x; u.h[1] = (f16)a.y; u.h[2] = (f16)a.z; u.h[3] = (f16)a.w;
    u.h[4] = (f16)b.x; u.h[5] = (f16)b.y; u.h[6] = (f16)b.z; u.h[7] = (f16)b.w;
    *(uint4*)(out + id * 8) = u.u;
}

// ---------------- Gram matrices: TRANS=0: C = pc^T@pc (512x512, K=256)
//                                 TRANS=1: C = pc@pc^T (256x256, K=512) -----------------
template <int TRANS>
__global__ __launch_bounds__(256) void k_gram(const float* __restrict__ pc,
                                              float* __restrict__ out) {
    constexpr int N = TRANS ? 256 : 512;
    constexpr int K = TRANS ? 512 : 256;
    __shared__ float As[16][68];
    __shared__ float Bs[16][68];
    int t = threadIdx.x;
    int i0 = blockIdx.x * 64, j0 = blockIdx.y * 64;
    int ty = t >> 4, tx = t & 15;
    float acc[4][4];
    #pragma unroll
    for (int r = 0; r < 4; r++)
        #pragma unroll
        for (int c = 0; c < 4; c++) acc[r][c] = 0.f;

    for (int kt = 0; kt < K; kt += 16) {
        if (TRANS == 0) {
            int k = t >> 4, c4 = t & 15;
            float4 va = *(const float4*)(pc + (size_t)(kt + k) * 512 + i0 + c4 * 4);
            float4 vb = *(const float4*)(pc + (size_t)(kt + k) * 512 + j0 + c4 * 4);
            *(float4*)&As[k][c4 * 4] = va;
            *(float4*)&Bs[k][c4 * 4] = vb;
        } else {
            int r = t >> 2, kc = t & 3;
            float4 va = *(const float4*)(pc + (size_t)(i0 + r) * 512 + kt + kc * 4);
            As[kc * 4 + 0][r] = va.x; As[kc * 4 + 1][r] = va.y;
            As[kc * 4 + 2][r] = va.z; As[kc * 4 + 3][r] = va.w;
            float4 vb = *(const float4*)(pc + (size_t)(j0 + r) * 512 + kt + kc * 4);
            Bs[kc * 4 + 0][r] = vb.x; Bs[kc * 4 + 1][r] = vb.y;
            Bs[kc * 4 + 2][r] = vb.z; Bs[kc * 4 + 3][r] = vb.w;
        }
        __syncthreads();
        #pragma unroll
        for (int u = 0; u < 16; u++) {
            float4 av = *(const float4*)&As[u][ty * 4];
            float4 bv = *(const float4*)&Bs[u][tx * 4];
            float aa[4] = {av.x, av.y, av.z, av.w};
            float bb[4] = {bv.x, bv.y, bv.z, bv.w};
            #pragma unroll
            for (int r = 0; r < 4; r++)
                #pragma unroll
                for (int c = 0; c < 4; c++) acc[r][c] += aa[r] * bb[c];
        }
        __syncthreads();
    }
    #pragma unroll
    for (int r = 0; r < 4; r++)
        #pragma unroll
        for (int c = 0; c < 4; c++)
            out[(size_t)(i0 + ty * 4 + r) * N + j0 + tx * 4 + c] = acc[r][c];
}

// ---------------- mask: M from precomputed gram blocks, then 1->50->1 MLP --------------
// Output pre-scaled by 0.125*log2(e): attn softmax runs in the exp2 domain.
__global__ __launch_bounds__(256) void k_mask(const float* __restrict__ pc,
                                              const float* __restrict__ nn,
                                              const float* __restrict__ nknk,
                                              const float* __restrict__ mw1,
                                              const float* __restrict__ mb1,
                                              const float* __restrict__ mw2,
                                              const float* __restrict__ mb2,
                                              float* __restrict__ maskp) {
    __shared__ float w1[50], b1[50], w2[50];
    int t = threadIdx.x;
    if (t < 50) { w1[t] = mw1[t]; b1[t] = mb1[t]; w2[t] = mw2[t]; }
    __syncthreads();
    int id = blockIdx.x * 256 + t;
    int i = id / 768, j = id - i * 768;
    float M;
    if (i < 512) M = (j < 512) ? nn[(size_t)i * 512 + j] : pc[(size_t)(j - 512) * 512 + i];
    else         M = (j < 512) ? pc[(size_t)(i - 512) * 512 + j]
                               : nknk[(size_t)(i - 512) * 256 + (j - 512)];
    float acc = mb2[0];
    #pragma unroll 10
    for (int u = 0; u < 50; u++) acc += fmaxf(M * w1[u] + b1[u], 0.f) * w2[u];
    maskp[id] = acc * 0.18033688011112042f;   // 0.125 * log2(e)
}

// ---------------- per-head V transpose: VT[bh][d=64][s=768] ----------------------------
__global__ __launch_bounds__(256) void k_vt(const f16* __restrict__ Vh,
                                            f16* __restrict__ VT) {
    __shared__ f16 tile[64][72];
    int t = threadIdx.x;
    int s0 = blockIdx.x * 64;
    int bh = blockIdx.y, b = bh >> 4, h = bh & 15;
    #pragma unroll
    for (int p = 0; p < 2; p++) {
        int cid = t + p * 256;           // 512 uint4 chunks: 64 s x 8 dc
        int s = cid >> 3, dc = cid & 7;
        *(uint4*)&tile[s][dc * 8] =
            *(const uint4*)(Vh + ((size_t)b * 768 + s0 + s) * 1024 + h * 64 + dc * 8);
    }
    __syncthreads();
    #pragma unroll
    for (int p = 0; p < 2; p++) {
        int cid = t + p * 256;
        int d = cid >> 3, sc = cid & 7;
        U4 u;
        #pragma unroll
        for (int j = 0; j < 8; j++) u.h[j] = tile[sc * 8 + j][d];
        *(uint4*)(VT + ((size_t)bh * 64 + d) * 768 + s0 + sc * 8) = u.u;
    }
}

// ---------------- deep-pipelined GEMM: C = A(12288x1024) @ W(1024x1024) + bias ---------
// 256x256 tile, BK=64, 8 waves (2M x 4N), 512 threads, LDS 128KB (2 K-tile buffers).
// Per K-tile: COMPUTE(buf) -> vmcnt(0)+raw barrier -> STAGE(buf, kt+2): each STAGE's 8
// global_load_lds have a full 64-MFMA compute group (~700cy) in flight before drain.
// Sync points 16 (vs 64 in the 2-barrier 128^2 loop). All tiles [128][64] f16 = 128B
// rows, 8x16B slots, involution swizzle slot^=(row&7) (pre-swizzled source + swizzled
// read; 2-way on LDS = free). C-fragment mapping identical to refcheck'd kernel.
// MODE 0: f16 out. MODE 1: f16 hi/lo split. MODE 2: fp32 out.
template <int MODE>
__global__ __launch_bounds__(512) void k_gemm8(const f16* __restrict__ A,
                                               const f16* __restrict__ Bt,
                                               const float* __restrict__ bias,
                                               void* out0v, void* out1v) {
    __shared__ f16 Ab[2][2][128 * 64];   // [buf][half][row*64+col]  64KB
    __shared__ f16 Bb[2][2][128 * 64];   //                          64KB
    int t = threadIdx.x;
    int w = t >> 6, lane = t & 63, l15 = lane & 15, quad = lane >> 4;
    int wm = w >> 2, wn = w & 3;         // 2M x 4N waves
    int id = blockIdx.x;                 // 192 = 48 row-panels x 4 col-panels; XCD id&7
    int c = id >> 3;                     // 0..23 per XCD
    int row0 = ((id & 7) * 6 + c % 6) * 256;
    int n0 = (c / 6) * 256;

    // staging: per half-tile 2 rounds; wave w covers rows p*64 + w*8 + (lane>>3),
    // physical slot lane&7 holds logical slot (lane&7)^(lane>>3)  [row&7 == lane>>3]
    int srow = lane >> 3;
    int ss = (lane & 7) ^ srow;
    const f16* gA = A + (size_t)(row0 + w * 8 + srow) * 1024 + ss * 8;
    const f16* gB = Bt + (size_t)(n0 + w * 8 + srow) * 1024 + ss * 8;

    auto STAGE = [&](int buf, int kt) {
        #pragma unroll
        for (int hf = 0; hf < 2; hf++)
            #pragma unroll
            for (int p = 0; p < 2; p++) {
                size_t roff = (size_t)(hf * 128 + p * 64) * 1024 + kt * 64;
                GLOAD16(gA + roff, &Ab[buf][hf][(p * 64 + w * 8) * 64]);
                GLOAD16(gB + roff, &Bb[buf][hf][(p * 64 + w * 8) * 64]);
            }
    };

    f32x4 acc[8][4];
    #pragma unroll
    for (int mi = 0; mi < 8; mi++)
        #pragma unroll
        for (int ni = 0; ni < 4; ni++) acc[mi][ni] = (f32x4){0.f, 0.f, 0.f, 0.f};

    int rx = l15 & 7;                    // read-side XOR (row&7 == l15&7 everywhere)

    auto COMPUTE = [&](int buf) {
        // B fragments held across the mi loop (8 ds_read_b128)
        f16x8 bf[4][2];
        #pragma unroll
        for (int ni = 0; ni < 4; ni++) {
            int row = wn * 64 + ni * 16 + l15;          // 0..255
            const char* bb = (const char*)&Bb[buf][row >> 7][0] +
                             (size_t)(row & 127) * 128;
            #pragma unroll
            for (int ks = 0; ks < 2; ks++)
                bf[ni][ks] = *(const f16x8*)(bb + (((ks * 4 + quad) ^ rx) << 4));
        }
        #pragma unroll
        for (int mi = 0; mi < 8; mi++) {
            int row = wm * 128 + mi * 16 + l15;
            const char* ab = (const char*)&Ab[buf][row >> 7][0] +
                             (size_t)(row & 127) * 128;
            f16x8 af0 = *(const f16x8*)(ab + (((0 + quad) ^ rx) << 4));
            f16x8 af1 = *(const f16x8*)(ab + (((4 + quad) ^ rx) << 4));
            #pragma unroll
            for (int ni = 0; ni < 4; ni++) {
                acc[mi][ni] = __builtin_amdgcn_mfma_f32_16x16x32_f16(af0, bf[ni][0],
                                                                     acc[mi][ni], 0, 0, 0);
                acc[mi][ni] = __builtin_amdgcn_mfma_f32_16x16x32_f16(af1, bf[ni][1],
                                                                     acc[mi][ni], 0, 0, 0);
            }
        }
    };

    STAGE(0, 0);
    asm volatile("s_waitcnt vmcnt(0)" ::: "memory");
    __builtin_amdgcn_s_barrier();        // buf0 ready
    STAGE(1, 1);                         // buf1 in flight under kt=0 compute
    for (int kt = 0; kt < 16; kt++) {
        int buf = kt & 1;
        COMPUTE(buf);
        asm volatile("s_waitcnt vmcnt(0)" ::: "memory");  // other buffer's loads landed
        __builtin_amdgcn_s_barrier();    // all waves done reading buf -> safe to restage
        if (kt + 2 < 16) STAGE(buf, kt + 2);
    }

    #pragma unroll
    for (int mi = 0; mi < 8; mi++) {
        #pragma unroll
        for (int ni = 0; ni < 4; ni++) {
            int col = n0 + wn * 64 + ni * 16 + l15;
            float bv = bias[col];
            #pragma unroll
            for (int r = 0; r < 4; r++) {
                int row = row0 + wm * 128 + mi * 16 + quad * 4 + r;
                float v = acc[mi][ni][r] + bv;
                size_t idx = (size_t)row * 1024 + col;
                if (MODE == 0) {
                    ((f16*)out0v)[idx] = (f16)v;
                } else if (MODE == 1) {
                    f16 hi = (f16)v;
                    ((f16*)out0v)[idx] = hi;
                    ((f16*)out1v)[idx] = (f16)(v - (float)hi);
                } else {
                    ((float*)out0v)[idx] = v;
                }
            }
        }
    }
}

// ---------------- flash attention, swapped QK^T (S^T fragments), split-f16 QK ----------
// mfma(K,Q) -> S^T: col=l15=q, row=quad*4+r=key. Per-lane q-state; exp2-domain softmax.
// LDS 48KB (3 blocks/CU): K hi/lo double-buffered, V SINGLE-buffered for the CURRENT
// tile with counted-vmcnt sync: V loads issued BEFORE the 4 K-prefetch loads, so
// mid-tile s_waitcnt vmcnt(4) (vmcnt is FIFO) guarantees V landed without draining the
// K prefetch. Raw s_barriers (no compiler auto-drain). End-of-tile vmcnt(0) covers the
// K prefetch (had the whole compute phase to land) + Vs WAR protection.
__global__ __launch_bounds__(256) void k_attn(const f16* __restrict__ Qhi,
                                              const f16* __restrict__ Qlo,
                                              const f16* __restrict__ Khi,
                                              const f16* __restrict__ Klo,
                                              const f16* __restrict__ VT,
                                              const float* __restrict__ maskp,
                                              f16* __restrict__ Xout) {
    __shared__ f16 Ksh[2][64 * 64];
    __shared__ f16 Ksl[2][64 * 64];
    __shared__ f16 Vs[64 * 64];      // Vs[d][s], single-buffered (current tile)
    __shared__ f16 Ps[4][16 * 64];   // per-wave P [q][key], swizzled 16B slots
    int t = threadIdx.x;
    int w = t >> 6, lane = t & 63, l15 = lane & 15, quad = lane >> 4;
    int id = blockIdx.x;             // 3072 = 256 bh x 12 q-tiles
    int bh = (id & 7) + ((id >> 3) / 12) * 8;
    int q0 = ((id >> 3) % 12) * 64;
    int b = bh >> 4, h = bh & 15;
    const size_t base = ((size_t)b * 768) * 1024 + h * 64;

    // staging geometry: wave w covers rows w*16 .. w*16+15, 2 rounds of 8 rows
    int srow = lane >> 3;            // 0..7 within round
    int sslot = lane & 7;

    f16x8 qh[2], ql[2];
    int qrow = q0 + w * 16 + l15;
    #pragma unroll
    for (int c = 0; c < 2; c++) {
        qh[c] = *(const f16x8*)(Qhi + base + (size_t)qrow * 1024 + c * 32 + quad * 8);
        ql[c] = *(const f16x8*)(Qlo + base + (size_t)qrow * 1024 + c * 32 + quad * 8);
    }
    // per-lane online-softmax state for q = q0 + w*16 + l15 (replicated across quads)
    float mrow = -1e30f, lrow = 0.f;
    f32x4 o[4];                      // O^T: d = ni*16 + quad*4 + r, q = l15
    #pragma unroll
    for (int ni = 0; ni < 4; ni++) o[ni] = (f32x4){0.f, 0.f, 0.f, 0.f};

    auto STAGE_K = [&](int bsel, int k0) {
        #pragma unroll
        for (int p = 0; p < 2; p++) {
            int row = w * 16 + p * 8 + srow;
            int ss = sslot ^ (row & 7);
            GLOAD16(Khi + base + (size_t)(k0 + row) * 1024 + ss * 8,
                    &Ksh[bsel][w * 1024 + p * 512]);
            GLOAD16(Klo + base + (size_t)(k0 + row) * 1024 + ss * 8,
                    &Ksl[bsel][w * 1024 + p * 512]);
        }
    };
    auto STAGE_V = [&](int k0) {
        #pragma unroll
        for (int p = 0; p < 2; p++) {
            int row = w * 16 + p * 8 + srow;
            int ss = sslot ^ (row & 7);
            GLOAD16(VT + ((size_t)bh * 64 + row) * 768 + k0 + ss * 8,
                    &Vs[w * 1024 + p * 512]);
        }
    };

    STAGE_K(0, 0);
    asm volatile("s_waitcnt vmcnt(0)" ::: "memory");
    __builtin_amdgcn_s_barrier();
    int buf = 0;
    int kx = l15 & 7;
    const float* mbase = maskp + (size_t)quad * 4 * 768 + q0 + w * 16 + l15;

    for (int kt = 0; kt < 12; kt++) {
        int k0 = kt * 64;
        // mask loads (coalesced over l15; symmetric mask indexed [key][q])
        float mvs[4][4];
        #pragma unroll
        for (int kn = 0; kn < 4; kn++)
            #pragma unroll
            for (int r = 0; r < 4; r++)
                mvs[kn][r] = mbase[(size_t)(k0 + kn * 16 + r) * 768];
        // V for CURRENT tile first (oldest), then K prefetch for next (4 newest)
        STAGE_V(k0);
        if (kt < 11) STAGE_K(buf ^ 1, k0 + 64);

        float sv[4][4];
        #pragma unroll
        for (int kn = 0; kn < 4; kn++) {
            f32x4 s = (f32x4){0.f, 0.f, 0.f, 0.f};
            int key = kn * 16 + l15;
            #pragma unroll
            for (int c = 0; c < 2; c++) {
                int slot = ((c << 2) + quad) ^ kx;
                f16x8 kh = *(const f16x8*)((const char*)&Ksh[buf][0] +
                                           (size_t)key * 128 + (slot << 4));
                f16x8 kl = *(const f16x8*)((const char*)&Ksl[buf][0] +
                                           (size_t)key * 128 + (slot << 4));
                s = __builtin_amdgcn_mfma_f32_16x16x32_f16(kh, qh[c], s, 0, 0, 0);
                s = __builtin_amdgcn_mfma_f32_16x16x32_f16(kh, ql[c], s, 0, 0, 0);
                s = __builtin_amdgcn_mfma_f32_16x16x32_f16(kl, qh[c], s, 0, 0, 0);
            }
            #pragma unroll
            for (int r = 0; r < 4; r++) sv[kn][r] = s[r] * mvs[kn][r];
        }

        // row max: fmax triples fuse to v_max3_f32; + 2 cross-quad shuffles
        float g0 = fmaxf(fmaxf(sv[0][0], sv[0][1]), sv[0][2]);
        float g1 = fmaxf(fmaxf(sv[0][3], sv[1][0]), sv[1][1]);
        float g2 = fmaxf(fmaxf(sv[1][2], sv[1][3]), sv[2][0]);
        float g3 = fmaxf(fmaxf(sv[2][1], sv[2][2]), sv[2][3]);
        float g4 = fmaxf(fmaxf(sv[3][0], sv[3][1]), sv[3][2]);
        float tm = fmaxf(fmaxf(fmaxf(g0, g1), fmaxf(g2, g3)), fmaxf(g4, sv[3][3]));
        tm = fmaxf(tm, __shfl_xor(tm, 16));
        tm = fmaxf(tm, __shfl_xor(tm, 32));
        // defer-max (THR = 11 in exp2 domain ~ 7.6 nats)
        if (__any(tm > mrow + 11.0f)) {
            float mn = fmaxf(mrow, tm);
            float alpha = exp2f(mrow - mn);
            mrow = mn;
            lrow *= alpha;
            #pragma unroll
            for (int ni = 0; ni < 4; ni++)
                #pragma unroll
                for (int r = 0; r < 4; r++) o[ni][r] *= alpha;
        }
        // exp2, row-sum, pack P (4 consecutive keys) -> swizzled ds_write_b64
        float rs = 0.f;
        #pragma unroll
        for (int kn = 0; kn < 4; kn++) {
            U2 pk;
            #pragma unroll
            for (int r = 0; r < 4; r++) {
                float pv = exp2f(sv[kn][r] - mrow);
                rs += pv;
                pk.h[r] = (f16)pv;
            }
            int slot = (kn * 2 + (quad >> 1)) ^ kx;
            *(uint2*)((char*)&Ps[w][0] + l15 * 128 + (slot << 4) + ((quad & 1) << 3)) = pk.u;
        }
        rs += __shfl_xor(rs, 16);
        rs += __shfl_xor(rs, 32);
        lrow += rs;

        asm volatile("s_waitcnt lgkmcnt(0)" ::: "memory");  // P write -> B-frag read (same wave)
        // V(cur) ready: FIFO vmcnt, V older than the 4 K-prefetch loads
        if (kt < 11) asm volatile("s_waitcnt vmcnt(4)" ::: "memory");
        else         asm volatile("s_waitcnt vmcnt(0)" ::: "memory");
        __builtin_amdgcn_s_barrier();    // all waves' V chunks visible
        __builtin_amdgcn_sched_barrier(0);
        #pragma unroll
        for (int c = 0; c < 2; c++) {
            int pslot = ((c << 2) + quad) ^ kx;
            f16x8 pa = *(const f16x8*)((const char*)&Ps[w][0] +
                                       (size_t)l15 * 128 + (pslot << 4));
            #pragma unroll
            for (int ni = 0; ni < 4; ni++) {
                int d = ni * 16 + l15;
                f16x8 vb = *(const f16x8*)((const char*)&Vs[0] +
                                           (size_t)d * 128 + (pslot << 4));
                o[ni] = __builtin_amdgcn_mfma_f32_16x16x32_f16(vb, pa, o[ni], 0, 0, 0);
            }
        }
        // K(next) landed (whole compute phase in flight); Vs consumed by all waves
        asm volatile("s_waitcnt vmcnt(0)" ::: "memory");
        __builtin_amdgcn_s_barrier();
        buf ^= 1;
    }
    // O^T -> packed coalescing-friendly stores: 4 f16 (r) per 8B, quads form 32B runs
    float rl = 1.0f / lrow;
    int qg = q0 + w * 16 + l15;
    #pragma unroll
    for (int ni = 0; ni < 4; ni++) {
        U2 ok;
        #pragma unroll
        for (int r = 0; r < 4; r++) ok.h[r] = (f16)(o[ni][r] * rl);
        *(uint2*)(Xout + ((size_t)b * 768 + qg) * 1024 + h * 64 + ni * 16 + quad * 4) = ok.u;
    }
}

// ---------------- launch ---------------------------------------------------------------
extern "C" void kernel_launch(void* const* d_in, const int* in_sizes, int n_in,
                              void* d_out, int out_size, void* d_ws, size_t ws_size,
                              hipStream_t stream) {
    (void)in_sizes; (void)n_in; (void)out_size; (void)ws_size;
    const float* query = (const float*)d_in[0];
    const float* key   = (const float*)d_in[1];
    const float* value = (const float*)d_in[2];
    const float* pc    = (const float*)d_in[3];
    const float* Wq    = (const float*)d_in[4];
    const float* bq    = (const float*)d_in[5];
    const float* Wk    = (const float*)d_in[6];
    const float* bk    = (const float*)d_in[7];
    const float* Wv    = (const float*)d_in[8];
    const float* bv    = (const float*)d_in[9];
    const float* Wo    = (const float*)d_in[10];
    const float* bo    = (const float*)d_in[11];
    const float* mw1   = (const float*)d_in[12];
    const float* mb1   = (const float*)d_in[13];
    const float* mw2   = (const float*)d_in[14];
    const float* mb2   = (const float*)d_in[15];

    char* p = (char*)d_ws;
    auto take = [&](size_t bytes) -> char* {
        char* r = p; p += (bytes + 255) & ~(size_t)255; return r;
    };
    const size_t NTOK = 12288, DM = 1024;
    float* maskb = (float*)take(768 * 768 * 4);
    float* nnb   = (float*)take(512 * 512 * 4);
    float* nknkb = (float*)take(256 * 256 * 4);
    f16* Wqt = (f16*)take(DM * DM * 2);
    f16* Wkt = (f16*)take(DM * DM * 2);
    f16* Wvt = (f16*)take(DM * DM * 2);
    f16* Wot = (f16*)take(DM * DM * 2);
    f16* buf1 = (f16*)take(NTOK * DM * 2);
    f16* Qhi = (f16*)take(NTOK * DM * 2);
    f16* Qlo = (f16*)take(NTOK * DM * 2);
    f16* Khi = (f16*)take(NTOK * DM * 2);
    f16* Klo = (f16*)take(NTOK * DM * 2);
    f16* Vhb = (f16*)take(NTOK * DM * 2);
    f16* VTb = (f16*)take(NTOK * DM * 2);

    k_wt<<<dim3(16, 16, 4), 256, 0, stream>>>(Wq, Wk, Wv, Wo, Wqt, Wkt, Wvt, Wot);
    k_gram<0><<<dim3(8, 8), 256, 0, stream>>>(pc, nnb);
    k_gram<1><<<dim3(4, 4), 256, 0, stream>>>(pc, nknkb);
    k_mask<<<2304, 256, 0, stream>>>(pc, nnb, nknkb, mw1, mb1, mw2, mb2, maskb);

    k_cvt<<<6144, 256, 0, stream>>>(query, buf1);
    k_gemm8<1><<<192, 512, 0, stream>>>(buf1, Wqt, bq, Qhi, Qlo);
    k_cvt<<<6144, 256, 0, stream>>>(key, buf1);
    k_gemm8<1><<<192, 512, 0, stream>>>(buf1, Wkt, bk, Khi, Klo);
    k_cvt<<<6144, 256, 0, stream>>>(value, buf1);
    k_gemm8<0><<<192, 512, 0, stream>>>(buf1, Wvt, bv, Vhb, nullptr);

    k_vt<<<dim3(12, 256), 256, 0, stream>>>(Vhb, VTb);

    k_attn<<<3072, 256, 0, stream>>>(Qhi, Qlo, Khi, Klo, VTb, maskb, buf1);

    k_gemm8<2><<<192, 512, 0, stream>>>(buf1, Wot, bo, d_out, nullptr);
}